// Round 1
// baseline (732.382 us; speedup 1.0000x reference)
//
#include <hip/hip_runtime.h>

typedef __bf16 bf16x4 __attribute__((ext_vector_type(4)));
typedef __bf16 bf16x8 __attribute__((ext_vector_type(8)));
typedef float  f32x4  __attribute__((ext_vector_type(4)));

#define HWSZ 4096
#define CCH  256
#define LOG2E 1.44269504088896340736f

enum { M_F32OUT = 0, M_CONVL = 1, M_CONVV = 2, M_PV = 3, M_G1 = 4, M_FUSE = 5 };

__device__ __forceinline__ float exp2_fast(float x) {
#if __has_builtin(__builtin_amdgcn_exp2f)
  return __builtin_amdgcn_exp2f(x);
#else
  return exp2f(x);
#endif
}

// stage 16B per lane into LDS; lane's data lands at lds_base + lane*16B
__device__ __forceinline__ void stage16(const __bf16* g, __bf16* ldsBase) {
#if __has_builtin(__builtin_amdgcn_global_load_lds)
  __builtin_amdgcn_global_load_lds(
      (const __attribute__((address_space(1))) void*)g,
      (__attribute__((address_space(3))) void*)ldsBase, 16, 0, 0);
#else
  int lane = threadIdx.x & 63;
  *(bf16x8*)(ldsBase + lane * 8) = *(const bf16x8*)g;
#endif
}

// ---------------------------------------------------------------------------
// Generic 128x128x32 bf16 MFMA GEMM, C = A * B^T with A[M,K], B[N,K] row-major
// (both K-contiguous). 256 threads = 4 waves in 2x2, each wave 64x64 (4x4
// 16x16x32 MFMA tiles). Epilogue selected by MODE.
// ---------------------------------------------------------------------------
template<int MODE>
__global__ __launch_bounds__(256)
void gemm_bt(const __bf16* __restrict__ A, long sAz,
             const __bf16* __restrict__ B, long sBz,
             int N, int K,
             __bf16* __restrict__ o0, __bf16* __restrict__ o1,
             __bf16* __restrict__ o2, __bf16* __restrict__ o3,
             long sOz,
             float* __restrict__ fout, long sFz,
             const float* __restrict__ bb0, const float* __restrict__ bb1,
             const float* __restrict__ bb2, const float* __restrict__ bb3,
             const float* __restrict__ resid, long sRz,
             const float* __restrict__ Slog, long sSz,
             const float* __restrict__ mst, const float* __restrict__ lst,
             int colOff)
{
  __shared__ __align__(16) __bf16 As[128 * 32];
  __shared__ __align__(16) __bf16 Bs[128 * 32];

  const int tid  = threadIdx.x;
  const int lane = tid & 63;
  const int w    = tid >> 6;
  const int wm   = (w >> 1) * 64;
  const int wn   = (w & 1) * 64;
  const int z    = blockIdx.z;
  const int bm   = blockIdx.y * 128;
  const int bn   = blockIdx.x * 128;

  const __bf16* Ab = A + (long)z * sAz;
  const __bf16* Bb = B + (long)z * sBz;

  f32x4 acc[4][4] = {};

  const int srow = lane >> 2;       // row within 16-row staging chunk
  const int skc  = (lane & 3) * 8;  // k-element offset within row

  for (int k0 = 0; k0 < K; k0 += 32) {
    if constexpr (MODE == M_PV) {
      // A-tile = P = exp(S - m_q) * linv_q, computed on the fly from fp32 logits
      const float* Sb = Slog + (long)z * sSz;
#pragma unroll
      for (int j = 0; j < 4; ++j) {
        int e = tid + j * 256;
        int r = e >> 3;
        int c = (e & 7) * 4;
        f32x4 s  = *(const f32x4*)(Sb + (long)(bm + r) * K + k0 + c);
        f32x4 mv = *(const f32x4*)(mst + z * HWSZ + k0 + c);
        f32x4 lv = *(const f32x4*)(lst + z * HWSZ + k0 + c);
        f32x4 p;
#pragma unroll
        for (int i = 0; i < 4; ++i)
          p[i] = exp2_fast((s[i] - mv[i]) * LOG2E) * lv[i];
        *(bf16x4*)(As + r * 32 + c) = __builtin_convertvector(p, bf16x4);
      }
    } else {
#pragma unroll
      for (int j = 0; j < 2; ++j) {
        int rbase = w * 32 + j * 16;
        stage16(Ab + (long)(bm + rbase + srow) * K + k0 + skc, As + rbase * 32);
      }
    }
#pragma unroll
    for (int j = 0; j < 2; ++j) {
      int rbase = w * 32 + j * 16;
      stage16(Bb + (long)(bn + rbase + srow) * K + k0 + skc, Bs + rbase * 32);
    }
    __syncthreads();

    bf16x8 af[4], bfr[4];
#pragma unroll
    for (int t = 0; t < 4; ++t)
      af[t] = *(const bf16x8*)(As + (wm + t * 16 + (lane & 15)) * 32 + (lane >> 4) * 8);
#pragma unroll
    for (int t = 0; t < 4; ++t)
      bfr[t] = *(const bf16x8*)(Bs + (wn + t * 16 + (lane & 15)) * 32 + (lane >> 4) * 8);
#pragma unroll
    for (int mt = 0; mt < 4; ++mt)
#pragma unroll
      for (int nt = 0; nt < 4; ++nt)
        acc[mt][nt] = __builtin_amdgcn_mfma_f32_16x16x32_bf16(af[mt], bfr[nt], acc[mt][nt], 0, 0, 0);
    __syncthreads();
  }

#pragma unroll
  for (int mt = 0; mt < 4; ++mt) {
#pragma unroll
    for (int nt = 0; nt < 4; ++nt) {
#pragma unroll
      for (int r = 0; r < 4; ++r) {
        int m = bm + wm + mt * 16 + (lane >> 4) * 4 + r;
        int n = bn + wn + nt * 16 + (lane & 15);
        float v = acc[mt][nt][r];
        if constexpr (MODE == M_F32OUT) {
          fout[(long)z * sFz + (long)m * N + n] = v;
        } else if constexpr (MODE == M_CONVL) {
          int g = m >> 8, mm = m & 255;
          const float* bb = (g == 0) ? bb0 : (g == 1) ? bb1 : (g == 2) ? bb2 : bb3;
          __bf16* op = (g == 0) ? o0 : (g == 1) ? o1 : (g == 2) ? o2 : o3;
          float vv = v + bb[mm];
          if (g == 2) op[(long)z * sOz + (long)mm * HWSZ + n] = (__bf16)vv;   // V: [c,p]
          else        op[(long)z * sOz + (long)n * CCH + mm] = (__bf16)vv;    // Q/K: [p,c]
        } else if constexpr (MODE == M_CONVV) {
          int g = m >> 8, mm = m & 255;
          const float* bb = g ? bb1 : bb0;
          __bf16* op = g ? o1 : o0;
          float vv = v + bb[mm];
          if (g) op[(long)z * sOz + (long)mm * HWSZ + n] = (__bf16)vv;        // Vc: [c,p]
          else   op[(long)z * sOz + (long)n * CCH + mm] = (__bf16)vv;         // Kc: [p,c]
        } else if constexpr (MODE == M_PV) {
          // scatter into "raw reshape + transpose" layout: buf[p, ci], p=(m&15)*256+n, ci=m>>4
          long adr = (long)((m & 15) * 256 + n) * 256 + (m >> 4);
          o0[(long)z * sOz + adr] = (__bf16)v;
        } else if constexpr (MODE == M_G1) {
          float vv = v + bb0[m] + resid[(long)z * sRz + (long)m * HWSZ + n];
          o0[(long)z * sOz + (long)n * 512 + m + colOff] = (__bf16)vv;        // ZZ: [p, 512]
        } else if constexpr (MODE == M_FUSE) {
          fout[(long)z * sFz + (long)m * HWSZ + n] = v + bb0[m];
        }
      }
    }
  }
}

// ---------------------------------------------------------------------------
// Fl/Fv [b][256][4096] fp32  ->  Xt [img][4096][256] bf16 (img: Fl b0, Fl b1, Fv b0, Fv b1)
__global__ void transpose_cvt(const float* __restrict__ F0, const float* __restrict__ F1,
                              __bf16* __restrict__ Xt) {
  __shared__ float tile[32][33];
  int img = blockIdx.z;
  const float* src = (img < 2 ? F0 : F1) + (long)(img & 1) * (CCH * HWSZ);
  __bf16* dst = Xt + (long)img * (HWSZ * CCH);
  int p0 = blockIdx.x * 32, c0 = blockIdx.y * 32;
  int tx = threadIdx.x, ty = threadIdx.y;
#pragma unroll
  for (int j = 0; j < 32; j += 8)
    tile[ty + j][tx] = src[(long)(c0 + ty + j) * HWSZ + p0 + tx];
  __syncthreads();
#pragma unroll
  for (int j = 0; j < 32; j += 8)
    dst[(long)(p0 + ty + j) * CCH + c0 + tx] = (__bf16)tile[tx][ty + j];
}

// Xt [img][4096][256] -> im2col Cc [img][4096][2304], k = t*256+ci, zero-padded borders
__global__ void im2col_k(const __bf16* __restrict__ Xt, __bf16* __restrict__ Cc) {
  int img = blockIdx.y;
  int e = blockIdx.x * 256 + threadIdx.x;          // < 4096*288
  int p = e / 288;
  int c8 = e - p * 288;
  int t = c8 >> 5;                                 // 0..8
  int ci0 = (c8 & 31) * 8;
  int dy = t / 3 - 1, dx = t - (t / 3) * 3 - 1;
  int y = p >> 6, x = p & 63;
  int yy = y + dy, xx = x + dx;
  const __bf16* src = Xt + (long)img * (HWSZ * CCH);
  __bf16* dst = Cc + (long)img * 9437184 + (long)p * 2304 + t * 256 + ci0;
  uint4 v = make_uint4(0u, 0u, 0u, 0u);
  if ((unsigned)yy < 64u && (unsigned)xx < 64u)
    v = *(const uint4*)(src + (long)(yy * 64 + xx) * CCH + ci0);
  *(uint4*)dst = v;
}

// W[co][ci][3][3] fp32 -> A[co][t*256+ci] bf16, stacked: AL rows 0..1023 (Wqs,Wks,Wvs,Wqc), AV (Wkc,Wvc)
struct W6 { const float* w[6]; };
__global__ void repack_w3(W6 wp, __bf16* __restrict__ AL, __bf16* __restrict__ AV) {
  int zi = blockIdx.y;
  int e = blockIdx.x * 256 + threadIdx.x;          // < 256*2304
  int co = e / 2304;
  int rem = e - co * 2304;
  int t = rem >> 8, ci = rem & 255;
  float v = wp.w[zi][(long)co * 2304 + ci * 9 + t];
  __bf16* dst = (zi < 4) ? (AL + (long)zi * 256 * 2304) : (AV + (long)(zi - 4) * 256 * 2304);
  dst[(long)co * 2304 + rem] = (__bf16)v;
}

__global__ void cvt_bf(const float* __restrict__ s, __bf16* __restrict__ d, int n) {
  int i = blockIdx.x * 256 + threadIdx.x;
  if (i < n) d[i] = (__bf16)s[i];
}

// Column-softmax stats over S[z][4096][4096] (softmax over rows, per column q)
__global__ void stats_partial(const float* __restrict__ S, float* __restrict__ pm, float* __restrict__ pl) {
  int q = blockIdx.x * 256 + threadIdx.x;
  int rc = blockIdx.y, z = blockIdx.z;
  const float* sp = S + (long)z * ((long)HWSZ * HWSZ) + (long)rc * 256 * HWSZ + q;
  float m = -3.0e38f, l = 0.0f;
  for (int i = 0; i < 256; ++i) {
    float x = sp[(long)i * HWSZ];
    float nm = fmaxf(m, x);
    l = l * exp2_fast((m - nm) * LOG2E) + exp2_fast((x - nm) * LOG2E);
    m = nm;
  }
  long o = ((long)z * 16 + rc) * HWSZ + q;
  pm[o] = m; pl[o] = l;
}

__global__ void stats_combine(const float* __restrict__ pm, const float* __restrict__ pl,
                              float* __restrict__ mst, float* __restrict__ lst) {
  int q = blockIdx.x * 256 + threadIdx.x;
  int z = blockIdx.y;
  float m = -3.0e38f;
#pragma unroll
  for (int rc = 0; rc < 16; ++rc) m = fmaxf(m, pm[((long)z * 16 + rc) * HWSZ + q]);
  float l = 0.f;
#pragma unroll
  for (int rc = 0; rc < 16; ++rc)
    l += pl[((long)z * 16 + rc) * HWSZ + q] * exp2_fast((pm[((long)z * 16 + rc) * HWSZ + q] - m) * LOG2E);
  mst[z * HWSZ + q] = m;
  lst[z * HWSZ + q] = 1.0f / l;
}

// ---------------------------------------------------------------------------
extern "C" void kernel_launch(void* const* d_in, const int* in_sizes, int n_in,
                              void* d_out, int out_size, void* d_ws, size_t ws_size,
                              hipStream_t stream) {
  const float* Fl  = (const float*)d_in[0];
  const float* Fv  = (const float*)d_in[1];
  const float* Wqs = (const float*)d_in[2];  const float* bqs = (const float*)d_in[3];
  const float* Wks = (const float*)d_in[4];  const float* bks = (const float*)d_in[5];
  const float* Wvs = (const float*)d_in[6];  const float* bvs = (const float*)d_in[7];
  const float* Wqc = (const float*)d_in[8];  const float* bqc = (const float*)d_in[9];
  const float* Wkc = (const float*)d_in[10]; const float* bkc = (const float*)d_in[11];
  const float* Wvc = (const float*)d_in[12]; const float* bvc = (const float*)d_in[13];
  const float* Wgs = (const float*)d_in[14]; const float* bgs = (const float*)d_in[15];
  const float* Wfu = (const float*)d_in[16]; const float* bfu = (const float*)d_in[17];

  char* ws = (char*)d_ws;
  size_t off = 0;
  auto take = [&](size_t bytes) -> void* {
    void* p = ws + off; off = (off + bytes + 255) & ~(size_t)255; return p;
  };
  __bf16* QST  = (__bf16*)take(4194304);   // Qs^T  [b][4096][256]
  __bf16* KST  = (__bf16*)take(4194304);
  __bf16* QCT  = (__bf16*)take(4194304);
  __bf16* KCT  = (__bf16*)take(4194304);
  __bf16* VS   = (__bf16*)take(4194304);   // Vs    [b][256][4096]
  __bf16* VC   = (__bf16*)take(4194304);
  __bf16* GT   = (__bf16*)take(4194304);   // reshape-transposed G [b][4096][256]
  __bf16* ZZ   = (__bf16*)take(8388608);   // concat [b][4096][512]
  __bf16* AL   = (__bf16*)take(4718592);   // stacked conv weights [1024][2304]
  __bf16* AV   = (__bf16*)take(2359296);   // [512][2304]
  __bf16* WGSb = (__bf16*)take(131072);
  __bf16* WFSb = (__bf16*)take(262144);
  float*  MST  = (float*)take(32768);
  float*  LST  = (float*)take(32768);
  float*  PM   = (float*)take(524288);
  float*  PL   = (float*)take(524288);
  size_t ovl = off;                         // overlay region
  __bf16* Xt = (__bf16*)take(8388608);      // conv phase only
  __bf16* Cc = (__bf16*)take(75497472);     // conv phase only
  size_t needConv = off;
  float* S = (float*)(ws + ovl);            // attention phase, overlays Xt/Cc
  size_t needAttn = ovl + 134217728;
  size_t need = needConv > needAttn ? needConv : needAttn;
  if (ws_size < need) return;               // fail cleanly instead of faulting

  const long Z1 = 1048576;                  // per-batch stride (elements) for 256x4096 mats

  transpose_cvt<<<dim3(128, 8, 4), dim3(32, 8), 0, stream>>>(Fl, Fv, Xt);
  im2col_k<<<dim3(4608, 4), 256, 0, stream>>>(Xt, Cc);
  W6 wp; wp.w[0]=Wqs; wp.w[1]=Wks; wp.w[2]=Wvs; wp.w[3]=Wqc; wp.w[4]=Wkc; wp.w[5]=Wvc;
  repack_w3<<<dim3(2304, 6), 256, 0, stream>>>(wp, AL, AV);
  cvt_bf<<<256, 256, 0, stream>>>(Wgs, WGSb, 65536);
  cvt_bf<<<512, 256, 0, stream>>>(Wfu, WFSb, 131072);

  // conv3x3 stacked GEMMs: M=1024 (Qs,Ks,Vs,Qc from Fl), M=512 (Kc,Vc from Fv)
  gemm_bt<M_CONVL><<<dim3(32, 8, 2), 256, 0, stream>>>(
      AL, 0, Cc, 9437184, 4096, 2304,
      QST, KST, VS, QCT, Z1,
      nullptr, 0,
      bqs, bks, bvs, bqc,
      nullptr, 0, nullptr, 0, nullptr, nullptr, 0);
  gemm_bt<M_CONVV><<<dim3(32, 4, 2), 256, 0, stream>>>(
      AV, 0, Cc + (long)2 * 9437184, 9437184, 4096, 2304,
      KCT, VC, nullptr, nullptr, Z1,
      nullptr, 0,
      bkc, bvc, nullptr, nullptr,
      nullptr, 0, nullptr, 0, nullptr, nullptr, 0);

  for (int br = 0; br < 2; ++br) {
    const __bf16* Qt = br ? QCT : QST;
    const __bf16* Kt = br ? KCT : KST;
    const __bf16* Vv = br ? VC  : VS;
    const float*  rs = br ? Fv  : Fl;
    // S = Q^T K  [b][4096 rows=k][4096 cols=q], fp32
    gemm_bt<M_F32OUT><<<dim3(32, 32, 2), 256, 0, stream>>>(
        Qt, Z1, Kt, Z1, 4096, 256,
        nullptr, nullptr, nullptr, nullptr, 0,
        S, (long)16777216,
        nullptr, nullptr, nullptr, nullptr,
        nullptr, 0, nullptr, 0, nullptr, nullptr, 0);
    stats_partial<<<dim3(16, 16, 2), 256, 0, stream>>>(S, PM, PL);
    stats_combine<<<dim3(16, 2), 256, 0, stream>>>(PM, PL, MST, LST);
    // G = P V^T with P computed in-staging from S + stats; scatter to GT
    gemm_bt<M_PV><<<dim3(2, 32, 2), 256, 0, stream>>>(
        nullptr, 0, Vv, Z1, 256, 4096,
        GT, nullptr, nullptr, nullptr, Z1,
        nullptr, 0,
        nullptr, nullptr, nullptr, nullptr,
        nullptr, 0,
        S, (long)16777216, MST, LST, 0);
    // 1x1 conv + bias + residual -> ZZ[:, br*256 .. br*256+255]
    gemm_bt<M_G1><<<dim3(32, 2, 2), 256, 0, stream>>>(
        WGSb, 0, GT, Z1, 4096, 256,
        ZZ, nullptr, nullptr, nullptr, (long)2097152,
        nullptr, 0,
        bgs, nullptr, nullptr, nullptr,
        rs, Z1,
        nullptr, 0, nullptr, nullptr, br * 256);
  }
  // fuse conv 1x1 over 512 channels -> fp32 out
  gemm_bt<M_FUSE><<<dim3(32, 2, 2), 256, 0, stream>>>(
      WFSb, 0, ZZ, (long)2097152, 4096, 512,
      nullptr, nullptr, nullptr, nullptr, 0,
      (float*)d_out, Z1,
      bfu, nullptr, nullptr, nullptr,
      nullptr, 0, nullptr, 0, nullptr, nullptr, 0);
}

// Round 2
// 718.905 us; speedup vs baseline: 1.0187x; 1.0187x over previous
//
#include <hip/hip_runtime.h>

typedef __bf16 bf16x4 __attribute__((ext_vector_type(4)));
typedef __bf16 bf16x8 __attribute__((ext_vector_type(8)));
typedef float  f32x4  __attribute__((ext_vector_type(4)));

#define HWSZ 4096
#define CCH  256
#define LOG2E 1.44269504088896340736f

enum { M_SSTAT = 0, M_CONVL = 1, M_CONVV = 2, M_PVK = 3, M_G1 = 4, M_FUSE = 5 };

__device__ __forceinline__ float exp2_fast(float x) {
#if __has_builtin(__builtin_amdgcn_exp2f)
  return __builtin_amdgcn_exp2f(x);
#else
  return exp2f(x);
#endif
}

// stage 16B per lane into LDS; lane's data lands at lds_base + lane*16B
__device__ __forceinline__ void stage16(const __bf16* g, __bf16* ldsBase) {
#if __has_builtin(__builtin_amdgcn_global_load_lds)
  __builtin_amdgcn_global_load_lds(
      (const __attribute__((address_space(1))) void*)g,
      (__attribute__((address_space(3))) void*)ldsBase, 16, 0, 0);
#else
  int lane = threadIdx.x & 63;
  *(bf16x8*)(ldsBase + lane * 8) = *(const bf16x8*)g;
#endif
}

// ---------------------------------------------------------------------------
// Generic 128x128x32 bf16 MFMA GEMM, C = A * B^T with A[M,K], B[N,K] row-major
// (both K-contiguous). 256 threads = 4 waves in 2x2, each wave 64x64 (4x4
// 16x16x32 MFMA tiles). Epilogue selected by MODE.
// M_PVK: blockIdx.z = K-slice (split-K over 16 slices of 256), A-tile computed
//        on the fly as P = exp(S - m)*linv from fp32 logits.
// M_SSTAT: writes fp32 S and per-128-row-chunk column softmax stats (pm, pl).
// ---------------------------------------------------------------------------
template<int MODE>
__global__ __launch_bounds__(256)
void gemm_bt(const __bf16* __restrict__ A, long sAz,
             const __bf16* __restrict__ B, long sBz,
             int N, int K,
             __bf16* __restrict__ o0, __bf16* __restrict__ o1,
             __bf16* __restrict__ o2, __bf16* __restrict__ o3,
             long sOz,
             float* __restrict__ fout, long sFz,
             const float* __restrict__ bb0, const float* __restrict__ bb1,
             const float* __restrict__ bb2, const float* __restrict__ bb3,
             const float* __restrict__ resid, long sRz,
             const float* __restrict__ Slog, long sSz,
             const float* __restrict__ mst, const float* __restrict__ lst,
             int colOff,
             float* __restrict__ pmo, float* __restrict__ plo)
{
  __shared__ __align__(16) __bf16 As[128 * 32];
  __shared__ __align__(16) __bf16 Bs[128 * 32];

  const int tid  = threadIdx.x;
  const int lane = tid & 63;
  const int w    = tid >> 6;
  const int wm   = (w >> 1) * 64;
  const int wn   = (w & 1) * 64;
  const int z    = (MODE == M_PVK) ? 0 : blockIdx.z;
  const int bm   = blockIdx.y * 128;
  const int bn   = blockIdx.x * 128;

  const __bf16* Ab = A + (long)z * sAz;
  const __bf16* Bb = B + (long)z * sBz;

  f32x4 acc[4][4] = {};

  const int srow = lane >> 2;       // row within 16-row staging chunk
  const int skc  = (lane & 3) * 8;  // k-element offset within row

  int kBeg = 0, kEnd = K;
  if constexpr (MODE == M_PVK) { kBeg = blockIdx.z * 256; kEnd = kBeg + 256; }

  for (int k0 = kBeg; k0 < kEnd; k0 += 32) {
    if constexpr (MODE == M_PVK) {
      // A-tile = P = exp(S - m_k) * linv_k, from fp32 logits (norm over contraction idx)
#pragma unroll
      for (int j = 0; j < 4; ++j) {
        int e = tid + j * 256;
        int r = e >> 3;
        int c = (e & 7) * 4;
        f32x4 s  = *(const f32x4*)(Slog + (long)(bm + r) * K + k0 + c);
        f32x4 mv = *(const f32x4*)(mst + k0 + c);
        f32x4 lv = *(const f32x4*)(lst + k0 + c);
        f32x4 p;
#pragma unroll
        for (int i = 0; i < 4; ++i)
          p[i] = exp2_fast((s[i] - mv[i]) * LOG2E) * lv[i];
        *(bf16x4*)(As + r * 32 + c) = __builtin_convertvector(p, bf16x4);
      }
    } else {
#pragma unroll
      for (int j = 0; j < 2; ++j) {
        int rbase = w * 32 + j * 16;
        stage16(Ab + (long)(bm + rbase + srow) * K + k0 + skc, As + rbase * 32);
      }
    }
#pragma unroll
    for (int j = 0; j < 2; ++j) {
      int rbase = w * 32 + j * 16;
      stage16(Bb + (long)(bn + rbase + srow) * K + k0 + skc, Bs + rbase * 32);
    }
    __syncthreads();

    bf16x8 af[4], bfr[4];
#pragma unroll
    for (int t = 0; t < 4; ++t)
      af[t] = *(const bf16x8*)(As + (wm + t * 16 + (lane & 15)) * 32 + (lane >> 4) * 8);
#pragma unroll
    for (int t = 0; t < 4; ++t)
      bfr[t] = *(const bf16x8*)(Bs + (wn + t * 16 + (lane & 15)) * 32 + (lane >> 4) * 8);
#pragma unroll
    for (int mt = 0; mt < 4; ++mt)
#pragma unroll
      for (int nt = 0; nt < 4; ++nt)
        acc[mt][nt] = __builtin_amdgcn_mfma_f32_16x16x32_bf16(af[mt], bfr[nt], acc[mt][nt], 0, 0, 0);
    __syncthreads();
  }

#pragma unroll
  for (int mt = 0; mt < 4; ++mt) {
#pragma unroll
    for (int nt = 0; nt < 4; ++nt) {
#pragma unroll
      for (int r = 0; r < 4; ++r) {
        int m = bm + wm + mt * 16 + (lane >> 4) * 4 + r;
        int n = bn + wn + nt * 16 + (lane & 15);
        float v = acc[mt][nt][r];
        if constexpr (MODE == M_SSTAT) {
          fout[(long)m * N + n] = v;
        } else if constexpr (MODE == M_CONVL) {
          int g = m >> 8, mm = m & 255;
          const float* bb = (g == 0) ? bb0 : (g == 1) ? bb1 : (g == 2) ? bb2 : bb3;
          __bf16* op = (g == 0) ? o0 : (g == 1) ? o1 : (g == 2) ? o2 : o3;
          float vv = v + bb[mm];
          if (g == 2) op[(long)z * sOz + (long)mm * HWSZ + n] = (__bf16)vv;   // V: [c,p]
          else        op[(long)z * sOz + (long)n * CCH + mm] = (__bf16)vv;    // Q/K: [p,c]
        } else if constexpr (MODE == M_CONVV) {
          int g = m >> 8, mm = m & 255;
          const float* bb = g ? bb1 : bb0;
          __bf16* op = g ? o1 : o0;
          float vv = v + bb[mm];
          if (g) op[(long)z * sOz + (long)mm * HWSZ + n] = (__bf16)vv;        // Vc: [c,p]
          else   op[(long)z * sOz + (long)n * CCH + mm] = (__bf16)vv;         // Kc: [p,c]
        } else if constexpr (MODE == M_PVK) {
          fout[(long)blockIdx.z * 1048576 + (long)m * 256 + n] = v;           // fp32 partial
        } else if constexpr (MODE == M_G1) {
          float vv = v + bb0[m] + resid[(long)z * sRz + (long)m * HWSZ + n];
          o0[(long)z * sOz + (long)n * 512 + m + colOff] = (__bf16)vv;        // ZZ: [p, 512]
        } else if constexpr (MODE == M_FUSE) {
          fout[(long)z * sFz + (long)m * HWSZ + n] = v + bb0[m];
        }
      }
    }
  }

  if constexpr (MODE == M_SSTAT) {
    // per-column (n) max / sumexp over this block's 128 rows, from fp32 accs
    __shared__ float sm_[4][64], sl_[4][64];
#pragma unroll
    for (int nt = 0; nt < 4; ++nt) {
      float mx = -3.0e38f;
#pragma unroll
      for (int mt = 0; mt < 4; ++mt)
#pragma unroll
        for (int r = 0; r < 4; ++r) mx = fmaxf(mx, acc[mt][nt][r]);
      float sl = 0.f;
#pragma unroll
      for (int mt = 0; mt < 4; ++mt)
#pragma unroll
        for (int r = 0; r < 4; ++r) sl += exp2_fast((acc[mt][nt][r] - mx) * LOG2E);
#pragma unroll
      for (int d = 16; d <= 32; d <<= 1) {
        float om = __shfl_xor(mx, d, 64);
        float ol = __shfl_xor(sl, d, 64);
        float nm = fmaxf(mx, om);
        sl = sl * exp2_fast((mx - nm) * LOG2E) + ol * exp2_fast((om - nm) * LOG2E);
        mx = nm;
      }
      if (lane < 16) { sm_[w][nt * 16 + lane] = mx; sl_[w][nt * 16 + lane] = sl; }
    }
    __syncthreads();
    if (tid < 128) {
      int hf = tid >> 6, c = tid & 63;
      float m1 = sm_[hf][c],     l1 = sl_[hf][c];
      float m2 = sm_[hf + 2][c], l2 = sl_[hf + 2][c];
      float nm = fmaxf(m1, m2);
      float ll = l1 * exp2_fast((m1 - nm) * LOG2E) + l2 * exp2_fast((m2 - nm) * LOG2E);
      pmo[(long)blockIdx.y * 4096 + bn + tid] = nm;
      plo[(long)blockIdx.y * 4096 + bn + tid] = ll;
    }
  }
}

// ---------------------------------------------------------------------------
// Sum 16 split-K fp32 partials [4096,256] and scatter into GT (reshape layout)
// block: (psub in [0,4), mchunk in [0,32)); handles p in [psub*1024, +1024),
// ci in [mchunk*8, +8). Source rows m = mchunk*128 + j*16 + psub*4 + dd.
__global__ __launch_bounds__(256)
void reduce_pv(const float* __restrict__ Gp, __bf16* __restrict__ GTz) {
  __shared__ __bf16 ch[32][256];
  const int t = threadIdx.x;
  const int psub = blockIdx.x, mc = blockIdx.y;
  const int dd = t >> 6;
  const int col = (t & 63) * 4;
  f32x4 acc[8] = {};
#pragma unroll
  for (int s = 0; s < 16; ++s) {
    const float* gp = Gp + (long)s * 1048576;
#pragma unroll
    for (int k = 0; k < 8; ++k) {
      int mm = k * 16 + psub * 4 + dd;
      f32x4 v = *(const f32x4*)(gp + (long)(mc * 128 + mm) * 256 + col);
      acc[k] += v;
    }
  }
#pragma unroll
  for (int k = 0; k < 8; ++k)
    *(bf16x4*)&ch[k * 4 + dd][col] = __builtin_convertvector(acc[k], bf16x4);
  __syncthreads();
#pragma unroll
  for (int it = 0; it < 4; ++it) {
    int p = psub * 1024 + it * 256 + t;
    bf16x8 v;
#pragma unroll
    for (int j = 0; j < 8; ++j) v[j] = ch[j * 4 + it][t];
    *(bf16x8*)(GTz + (long)p * 256 + mc * 8) = v;
  }
}

// ---------------------------------------------------------------------------
// Fl/Fv [b][256][4096] fp32  ->  Xt [img][4096][256] bf16 (img: Fl b0, Fl b1, Fv b0, Fv b1)
__global__ void transpose_cvt(const float* __restrict__ F0, const float* __restrict__ F1,
                              __bf16* __restrict__ Xt) {
  __shared__ float tile[32][33];
  int img = blockIdx.z;
  const float* src = (img < 2 ? F0 : F1) + (long)(img & 1) * (CCH * HWSZ);
  __bf16* dst = Xt + (long)img * (HWSZ * CCH);
  int p0 = blockIdx.x * 32, c0 = blockIdx.y * 32;
  int tx = threadIdx.x, ty = threadIdx.y;
#pragma unroll
  for (int j = 0; j < 32; j += 8)
    tile[ty + j][tx] = src[(long)(c0 + ty + j) * HWSZ + p0 + tx];
  __syncthreads();
#pragma unroll
  for (int j = 0; j < 32; j += 8)
    dst[(long)(p0 + ty + j) * CCH + c0 + tx] = (__bf16)tile[tx][ty + j];
}

// Xt [img][4096][256] -> im2col Cc [img][4096][2304], k = t*256+ci, zero-padded borders
__global__ void im2col_k(const __bf16* __restrict__ Xt, __bf16* __restrict__ Cc) {
  int img = blockIdx.y;
  int e = blockIdx.x * 256 + threadIdx.x;          // < 4096*288
  int p = e / 288;
  int c8 = e - p * 288;
  int t = c8 >> 5;                                 // 0..8
  int ci0 = (c8 & 31) * 8;
  int dy = t / 3 - 1, dx = t - (t / 3) * 3 - 1;
  int y = p >> 6, x = p & 63;
  int yy = y + dy, xx = x + dx;
  const __bf16* src = Xt + (long)img * (HWSZ * CCH);
  __bf16* dst = Cc + (long)img * 9437184 + (long)p * 2304 + t * 256 + ci0;
  uint4 v = make_uint4(0u, 0u, 0u, 0u);
  if ((unsigned)yy < 64u && (unsigned)xx < 64u)
    v = *(const uint4*)(src + (long)(yy * 64 + xx) * CCH + ci0);
  *(uint4*)dst = v;
}

// W[co][ci][3][3] fp32 -> A[co][t*256+ci] bf16, stacked: AL rows (Wqs,Wks,Wvs,Wqc), AV (Wkc,Wvc)
struct W6 { const float* w[6]; };
__global__ void repack_w3(W6 wp, __bf16* __restrict__ AL, __bf16* __restrict__ AV) {
  int zi = blockIdx.y;
  int e = blockIdx.x * 256 + threadIdx.x;          // < 256*2304
  int co = e / 2304;
  int rem = e - co * 2304;
  int t = rem >> 8, ci = rem & 255;
  float v = wp.w[zi][(long)co * 2304 + ci * 9 + t];
  __bf16* dst = (zi < 4) ? (AL + (long)zi * 256 * 2304) : (AV + (long)(zi - 4) * 256 * 2304);
  dst[(long)co * 2304 + rem] = (__bf16)v;
}

__global__ void cvt_bf(const float* __restrict__ s, __bf16* __restrict__ d, int n) {
  int i = blockIdx.x * 256 + threadIdx.x;
  if (i < n) d[i] = (__bf16)s[i];
}

// combine 32 row-chunk partial stats -> column max + 1/sumexp
__global__ void stats_combine(const float* __restrict__ pm, const float* __restrict__ pl,
                              float* __restrict__ mst, float* __restrict__ lst) {
  int q = blockIdx.x * 256 + threadIdx.x;
  float m = -3.0e38f;
#pragma unroll
  for (int rc = 0; rc < 32; ++rc) m = fmaxf(m, pm[(long)rc * 4096 + q]);
  float l = 0.f;
#pragma unroll
  for (int rc = 0; rc < 32; ++rc)
    l += pl[(long)rc * 4096 + q] * exp2_fast((pm[(long)rc * 4096 + q] - m) * LOG2E);
  mst[q] = m;
  lst[q] = 1.0f / l;
}

// ---------------------------------------------------------------------------
extern "C" void kernel_launch(void* const* d_in, const int* in_sizes, int n_in,
                              void* d_out, int out_size, void* d_ws, size_t ws_size,
                              hipStream_t stream) {
  const float* Fl  = (const float*)d_in[0];
  const float* Fv  = (const float*)d_in[1];
  const float* Wqs = (const float*)d_in[2];  const float* bqs = (const float*)d_in[3];
  const float* Wks = (const float*)d_in[4];  const float* bks = (const float*)d_in[5];
  const float* Wvs = (const float*)d_in[6];  const float* bvs = (const float*)d_in[7];
  const float* Wqc = (const float*)d_in[8];  const float* bqc = (const float*)d_in[9];
  const float* Wkc = (const float*)d_in[10]; const float* bkc = (const float*)d_in[11];
  const float* Wvc = (const float*)d_in[12]; const float* bvc = (const float*)d_in[13];
  const float* Wgs = (const float*)d_in[14]; const float* bgs = (const float*)d_in[15];
  const float* Wfu = (const float*)d_in[16]; const float* bfu = (const float*)d_in[17];

  char* ws = (char*)d_ws;
  size_t off = 0;
  auto take = [&](size_t bytes) -> void* {
    void* p = ws + off; off = (off + bytes + 255) & ~(size_t)255; return p;
  };
  __bf16* QST  = (__bf16*)take(4194304);   // Qs^T  [b][4096][256]
  __bf16* KST  = (__bf16*)take(4194304);
  __bf16* QCT  = (__bf16*)take(4194304);
  __bf16* KCT  = (__bf16*)take(4194304);
  __bf16* VS   = (__bf16*)take(4194304);   // Vs    [b][256][4096]
  __bf16* VC   = (__bf16*)take(4194304);
  __bf16* GT   = (__bf16*)take(4194304);   // reshape-transposed G [b][4096][256]
  __bf16* ZZ   = (__bf16*)take(8388608);   // concat [b][4096][512]
  __bf16* AL   = (__bf16*)take(4718592);   // stacked conv weights [1024][2304]
  __bf16* AV   = (__bf16*)take(2359296);   // [512][2304]
  __bf16* WGSb = (__bf16*)take(131072);
  __bf16* WFSb = (__bf16*)take(262144);
  float*  MST  = (float*)take(32768);
  float*  LST  = (float*)take(32768);
  float*  PM   = (float*)take(524288);     // [32][4096]
  float*  PL   = (float*)take(524288);
  size_t ovl = off;                         // overlay region
  __bf16* Xt = (__bf16*)take(8388608);      // conv phase only
  __bf16* Cc = (__bf16*)take(75497472);     // conv phase only
  size_t needConv = off;
  float* S  = (float*)(ws + ovl);           // attn phase: one (br,z): 64 MB
  float* Gp = (float*)(ws + ovl + 67108864);// split-K partials: 16 x [4096,256] fp32
  size_t needAttn = ovl + 134217728;
  size_t need = needConv > needAttn ? needConv : needAttn;
  if (ws_size < need) return;               // fail cleanly instead of faulting

  const long Z1 = 1048576;                  // per-batch stride (elements) for 256x4096 mats

  transpose_cvt<<<dim3(128, 8, 4), dim3(32, 8), 0, stream>>>(Fl, Fv, Xt);
  im2col_k<<<dim3(4608, 4), 256, 0, stream>>>(Xt, Cc);
  W6 wp; wp.w[0]=Wqs; wp.w[1]=Wks; wp.w[2]=Wvs; wp.w[3]=Wqc; wp.w[4]=Wkc; wp.w[5]=Wvc;
  repack_w3<<<dim3(2304, 6), 256, 0, stream>>>(wp, AL, AV);
  cvt_bf<<<256, 256, 0, stream>>>(Wgs, WGSb, 65536);
  cvt_bf<<<512, 256, 0, stream>>>(Wfu, WFSb, 131072);

  // conv3x3 stacked GEMMs: M=1024 (Qs,Ks,Vs,Qc from Fl), M=512 (Kc,Vc from Fv)
  gemm_bt<M_CONVL><<<dim3(32, 8, 2), 256, 0, stream>>>(
      AL, 0, Cc, 9437184, 4096, 2304,
      QST, KST, VS, QCT, Z1,
      nullptr, 0,
      bqs, bks, bvs, bqc,
      nullptr, 0, nullptr, 0, nullptr, nullptr, 0, nullptr, nullptr);
  gemm_bt<M_CONVV><<<dim3(32, 4, 2), 256, 0, stream>>>(
      AV, 0, Cc + (long)2 * 9437184, 9437184, 4096, 2304,
      KCT, VC, nullptr, nullptr, Z1,
      nullptr, 0,
      bkc, bvc, nullptr, nullptr,
      nullptr, 0, nullptr, 0, nullptr, nullptr, 0, nullptr, nullptr);

  for (int br = 0; br < 2; ++br) {
    const __bf16* Qt = br ? QCT : QST;
    const __bf16* Kt = br ? KCT : KST;
    const __bf16* Vv = br ? VC  : VS;
    const float*  rs = br ? Fv  : Fl;
    for (int z = 0; z < 2; ++z) {
      // S = Q^T K [4096,4096] fp32 + fused per-128-row-chunk column stats
      gemm_bt<M_SSTAT><<<dim3(32, 32, 1), 256, 0, stream>>>(
          Qt + z * Z1, 0, Kt + z * Z1, 0, 4096, 256,
          nullptr, nullptr, nullptr, nullptr, 0,
          S, 0,
          nullptr, nullptr, nullptr, nullptr,
          nullptr, 0, nullptr, 0, nullptr, nullptr, 0, PM, PL);
      stats_combine<<<dim3(16), 256, 0, stream>>>(PM, PL, MST + z * HWSZ, LST + z * HWSZ);
      // split-K PV: G_partial[ks] = P[:, ks*256:+256] * V^T chunk
      gemm_bt<M_PVK><<<dim3(2, 32, 16), 256, 0, stream>>>(
          nullptr, 0, Vv + z * Z1, 0, 256, 4096,
          nullptr, nullptr, nullptr, nullptr, 0,
          Gp, 0,
          nullptr, nullptr, nullptr, nullptr,
          nullptr, 0,
          S, 0, MST + z * HWSZ, LST + z * HWSZ, 0, nullptr, nullptr);
      reduce_pv<<<dim3(4, 32), 256, 0, stream>>>(Gp, GT + z * Z1);
    }
    // 1x1 conv + bias + residual -> ZZ[:, br*256 .. br*256+255]
    gemm_bt<M_G1><<<dim3(32, 2, 2), 256, 0, stream>>>(
        WGSb, 0, GT, Z1, 4096, 256,
        ZZ, nullptr, nullptr, nullptr, (long)2097152,
        nullptr, 0,
        bgs, nullptr, nullptr, nullptr,
        rs, Z1,
        nullptr, 0, nullptr, nullptr, br * 256, nullptr, nullptr);
  }
  // fuse conv 1x1 over 512 channels -> fp32 out
  gemm_bt<M_FUSE><<<dim3(32, 2, 2), 256, 0, stream>>>(
      WFSb, 0, ZZ, (long)2097152, 4096, 512,
      nullptr, nullptr, nullptr, nullptr, 0,
      (float*)d_out, Z1,
      bfu, nullptr, nullptr, nullptr,
      nullptr, 0, nullptr, 0, nullptr, nullptr, 0, nullptr, nullptr);
}

// Round 3
// 537.407 us; speedup vs baseline: 1.3628x; 1.3377x over previous
//
#include <hip/hip_runtime.h>

typedef __bf16 bf16x4 __attribute__((ext_vector_type(4)));
typedef __bf16 bf16x8 __attribute__((ext_vector_type(8)));
typedef float  f32x4  __attribute__((ext_vector_type(4)));

#define HWSZ 4096
#define CCH  256
#define LOG2E 1.44269504088896340736f

enum { M_SSTAT = 0, M_CONVL = 1, M_CONVV = 2, M_PVK = 3, M_G1 = 4, M_FUSE = 5 };

__device__ __forceinline__ float exp2_fast(float x) {
#if __has_builtin(__builtin_amdgcn_exp2f)
  return __builtin_amdgcn_exp2f(x);
#else
  return exp2f(x);
#endif
}

// stage 16B per lane into LDS; lane's data lands at lds_base + lane*16B
__device__ __forceinline__ void stage16(const __bf16* g, __bf16* ldsBase) {
#if __has_builtin(__builtin_amdgcn_global_load_lds)
  __builtin_amdgcn_global_load_lds(
      (const __attribute__((address_space(1))) void*)g,
      (__attribute__((address_space(3))) void*)ldsBase, 16, 0, 0);
#else
  int lane = threadIdx.x & 63;
  *(bf16x8*)(ldsBase + lane * 8) = *(const bf16x8*)g;
#endif
}

// ---------------------------------------------------------------------------
// Generic 128x128x32 bf16 MFMA GEMM, C = A * B^T with A[M,K], B[N,K] row-major
// (both K-contiguous). 256 threads = 4 waves in 2x2, each wave 64x64 (4x4
// 16x16x32 MFMA tiles). Epilogue selected by MODE.
// M_SSTAT: z-batched; stores Pb = exp(S - m_block) bf16 via coalesced LDS
//          repack + per-(rowblock,column) stats pm/pl.
// M_PVK:   blockIdx.z = bz*8 + slice (split-K 8 x 512); A-tile staged from Pb
//          bf16 scaled by f[k] = exp(pm_blk - m)*linv (precomputed in LDS).
// ---------------------------------------------------------------------------
template<int MODE>
__global__ __launch_bounds__(256)
void gemm_bt(const __bf16* __restrict__ A, long sAz,
             const __bf16* __restrict__ B, long sBz,
             int N, int K,
             __bf16* __restrict__ o0, __bf16* __restrict__ o1,
             __bf16* __restrict__ o2, __bf16* __restrict__ o3,
             long sOz,
             float* __restrict__ fout, long sFz,
             const float* __restrict__ bb0, const float* __restrict__ bb1,
             const float* __restrict__ bb2, const float* __restrict__ bb3,
             const float* __restrict__ resid, long sRz,
             const float* __restrict__ mst, const float* __restrict__ lst,
             int colOff,
             float* __restrict__ pmo, float* __restrict__ plo)
{
  __shared__ __align__(16) __bf16 smem[8192];   // As | Bs, reused as epilogue buf
  __bf16* As = smem;
  __bf16* Bs = smem + 4096;

  const int tid  = threadIdx.x;
  const int lane = tid & 63;
  const int w    = tid >> 6;
  const int wm   = (w >> 1) * 64;
  const int wn   = (w & 1) * 64;
  const int z    = (MODE == M_PVK) ? (int)(blockIdx.z >> 3) : blockIdx.z;
  const int bm   = blockIdx.y * 128;
  const int bn   = blockIdx.x * 128;

  const __bf16* Ab = A + (long)z * sAz;
  const __bf16* Bb = B + (long)z * sBz;

  f32x4 acc[4][4] = {};

  const int srow = lane >> 2;       // row within 16-row staging chunk
  const int skc  = (lane & 3) * 8;  // k-element offset within row

  int kBeg = 0, kEnd = K;
#if 1
  if constexpr (MODE == M_PVK) {
    int slice = blockIdx.z & 7;
    kBeg = slice * 512; kEnd = kBeg + 512;
  }
#endif

  if constexpr (MODE == M_PVK) {
    // f[k] = exp(pm_blk[k] - m[k]) * linv[k] for this block's row-chunk
    __shared__ float ff_[512];
    const float* pmrow = pmo + ((long)z * 32 + (bm >> 7)) * 4096;
    for (int i = tid; i < 512; i += 256) {
      int k = kBeg + i;
      ff_[i] = exp2_fast((pmrow[k] - mst[(long)z * 4096 + k]) * LOG2E) * lst[(long)z * 4096 + k];
    }
    __syncthreads();

    for (int k0 = kBeg; k0 < kEnd; k0 += 32) {
      // A-tile = Pb * f (bf16 in, fp32 scale, bf16 out)
#pragma unroll
      for (int j = 0; j < 2; ++j) {
        int e = tid + j * 256;
        int r = e >> 2;
        int c8 = (e & 3) * 8;
        bf16x8 v8 = *(const bf16x8*)(Ab + (long)(bm + r) * 4096 + k0 + c8);
        bf16x8 o;
#pragma unroll
        for (int i = 0; i < 8; ++i)
          o[i] = (__bf16)((float)v8[i] * ff_[k0 - kBeg + c8 + i]);
        *(bf16x8*)(As + r * 32 + c8) = o;
      }
#pragma unroll
      for (int j = 0; j < 2; ++j) {
        int rbase = w * 32 + j * 16;
        stage16(Bb + (long)(bn + rbase + srow) * K + k0 + skc, Bs + rbase * 32);
      }
      __syncthreads();
      bf16x8 af[4], bfr[4];
#pragma unroll
      for (int t = 0; t < 4; ++t)
        af[t] = *(const bf16x8*)(As + (wm + t * 16 + (lane & 15)) * 32 + (lane >> 4) * 8);
#pragma unroll
      for (int t = 0; t < 4; ++t)
        bfr[t] = *(const bf16x8*)(Bs + (wn + t * 16 + (lane & 15)) * 32 + (lane >> 4) * 8);
#pragma unroll
      for (int mt = 0; mt < 4; ++mt)
#pragma unroll
        for (int nt = 0; nt < 4; ++nt)
          acc[mt][nt] = __builtin_amdgcn_mfma_f32_16x16x32_bf16(af[mt], bfr[nt], acc[mt][nt], 0, 0, 0);
      __syncthreads();
    }
  } else {
    for (int k0 = kBeg; k0 < kEnd; k0 += 32) {
#pragma unroll
      for (int j = 0; j < 2; ++j) {
        int rbase = w * 32 + j * 16;
        stage16(Ab + (long)(bm + rbase + srow) * K + k0 + skc, As + rbase * 32);
      }
#pragma unroll
      for (int j = 0; j < 2; ++j) {
        int rbase = w * 32 + j * 16;
        stage16(Bb + (long)(bn + rbase + srow) * K + k0 + skc, Bs + rbase * 32);
      }
      __syncthreads();
      bf16x8 af[4], bfr[4];
#pragma unroll
      for (int t = 0; t < 4; ++t)
        af[t] = *(const bf16x8*)(As + (wm + t * 16 + (lane & 15)) * 32 + (lane >> 4) * 8);
#pragma unroll
      for (int t = 0; t < 4; ++t)
        bfr[t] = *(const bf16x8*)(Bs + (wn + t * 16 + (lane & 15)) * 32 + (lane >> 4) * 8);
#pragma unroll
      for (int mt = 0; mt < 4; ++mt)
#pragma unroll
        for (int nt = 0; nt < 4; ++nt)
          acc[mt][nt] = __builtin_amdgcn_mfma_f32_16x16x32_bf16(af[mt], bfr[nt], acc[mt][nt], 0, 0, 0);
      __syncthreads();
    }
  }

  if constexpr (MODE != M_SSTAT) {
#pragma unroll
    for (int mt = 0; mt < 4; ++mt) {
#pragma unroll
      for (int nt = 0; nt < 4; ++nt) {
#pragma unroll
        for (int r = 0; r < 4; ++r) {
          int m = bm + wm + mt * 16 + (lane >> 4) * 4 + r;
          int n = bn + wn + nt * 16 + (lane & 15);
          float v = acc[mt][nt][r];
          if constexpr (MODE == M_CONVL) {
            int g = m >> 8, mm = m & 255;
            const float* bb = (g == 0) ? bb0 : (g == 1) ? bb1 : (g == 2) ? bb2 : bb3;
            __bf16* op = (g == 0) ? o0 : (g == 1) ? o1 : (g == 2) ? o2 : o3;
            float vv = v + bb[mm];
            if (g == 2) op[(long)z * sOz + (long)mm * HWSZ + n] = (__bf16)vv;   // V: [c,p]
            else        op[(long)z * sOz + (long)n * CCH + mm] = (__bf16)vv;    // Q/K: [p,c]
          } else if constexpr (MODE == M_CONVV) {
            int g = m >> 8, mm = m & 255;
            const float* bb = g ? bb1 : bb0;
            __bf16* op = g ? o1 : o0;
            float vv = v + bb[mm];
            if (g) op[(long)z * sOz + (long)mm * HWSZ + n] = (__bf16)vv;        // Vc: [c,p]
            else   op[(long)z * sOz + (long)n * CCH + mm] = (__bf16)vv;         // Kc: [p,c]
          } else if constexpr (MODE == M_PVK) {
            fout[(long)blockIdx.z * 1048576 + (long)m * 256 + n] = v;           // fp32 partial
          } else if constexpr (MODE == M_G1) {
            float vv = v + bb0[m] + resid[(long)z * sRz + (long)m * HWSZ + n];
            o0[(long)z * sOz + (long)n * 512 + m + colOff] = (__bf16)vv;        // ZZ: [p, 512]
          } else if constexpr (MODE == M_FUSE) {
            fout[(long)z * sFz + (long)m * HWSZ + n] = v + bb0[m];
          }
        }
      }
    }
  }

  if constexpr (MODE == M_SSTAT) {
    // 1) per-column stats over the block's 128 rows
    __shared__ float sm_[4][64], sl_[4][64], mcol[128];
#pragma unroll
    for (int nt = 0; nt < 4; ++nt) {
      float mx = -3.0e38f;
#pragma unroll
      for (int mt = 0; mt < 4; ++mt)
#pragma unroll
        for (int r = 0; r < 4; ++r) mx = fmaxf(mx, acc[mt][nt][r]);
      float sl = 0.f;
#pragma unroll
      for (int mt = 0; mt < 4; ++mt)
#pragma unroll
        for (int r = 0; r < 4; ++r) sl += exp2_fast((acc[mt][nt][r] - mx) * LOG2E);
#pragma unroll
      for (int d = 16; d <= 32; d <<= 1) {
        float om = __shfl_xor(mx, d, 64);
        float ol = __shfl_xor(sl, d, 64);
        float nm = fmaxf(mx, om);
        sl = sl * exp2_fast((mx - nm) * LOG2E) + ol * exp2_fast((om - nm) * LOG2E);
        mx = nm;
      }
      if (lane < 16) { sm_[w][nt * 16 + lane] = mx; sl_[w][nt * 16 + lane] = sl; }
    }
    __syncthreads();
    if (tid < 128) {
      int hf = tid >> 6, c = tid & 63;
      float m1 = sm_[hf][c],     l1 = sl_[hf][c];
      float m2 = sm_[hf + 2][c], l2 = sl_[hf + 2][c];
      float nm = fmaxf(m1, m2);
      float ll = l1 * exp2_fast((m1 - nm) * LOG2E) + l2 * exp2_fast((m2 - nm) * LOG2E);
      pmo[((long)z * 32 + blockIdx.y) * 4096 + bn + tid] = nm;
      plo[((long)z * 32 + blockIdx.y) * 4096 + bn + tid] = ll;
      mcol[tid] = nm;
    }
    __syncthreads();
    // 2) Pb = exp(acc - m_col) bf16, coalesced via LDS repack (two halves by m)
    __bf16* Ps = smem;                         // [64][128] bf16 = 16 KB
    for (int h = 0; h < 2; ++h) {
      if ((w >> 1) == h) {
#pragma unroll
        for (int nt = 0; nt < 4; ++nt) {
          int ln = wn + nt * 16 + (lane & 15);
          float mc = mcol[ln];
#pragma unroll
          for (int mt = 0; mt < 4; ++mt)
#pragma unroll
            for (int r = 0; r < 4; ++r) {
              int lm = (wm - h * 64) + mt * 16 + (lane >> 4) * 4 + r;
              Ps[lm * 128 + ln] = (__bf16)exp2_fast((acc[mt][nt][r] - mc) * LOG2E);
            }
        }
      }
      __syncthreads();
      int rt = tid >> 4, l16 = tid & 15;
#pragma unroll
      for (int rr = 0; rr < 4; ++rr) {
        int lr = rr * 16 + rt;
        *(bf16x8*)(o0 + (long)z * sOz + (long)(bm + h * 64 + lr) * 4096 + bn + l16 * 8)
            = *(const bf16x8*)&Ps[lr * 128 + l16 * 8];
      }
      __syncthreads();
    }
  }
}

// ---------------------------------------------------------------------------
// Sum 8 split-K fp32 partials [4096,256] and scatter into GT (reshape layout)
__global__ __launch_bounds__(256)
void reduce_pv(const float* __restrict__ Gp, __bf16* __restrict__ GT) {
  __shared__ __bf16 ch[32][256];
  const int t = threadIdx.x;
  const int psub = blockIdx.x, mc = blockIdx.y, bz = blockIdx.z;
  const float* base = Gp + (long)bz * 8388608;
  __bf16* GTz = GT + (long)bz * 1048576;
  const int dd = t >> 6;
  const int col = (t & 63) * 4;
  f32x4 acc[8] = {};
#pragma unroll
  for (int s = 0; s < 8; ++s) {
    const float* gp = base + (long)s * 1048576;
#pragma unroll
    for (int k = 0; k < 8; ++k) {
      int mm = k * 16 + psub * 4 + dd;
      f32x4 v = *(const f32x4*)(gp + (long)(mc * 128 + mm) * 256 + col);
      acc[k] += v;
    }
  }
#pragma unroll
  for (int k = 0; k < 8; ++k)
    *(bf16x4*)&ch[k * 4 + dd][col] = __builtin_convertvector(acc[k], bf16x4);
  __syncthreads();
#pragma unroll
  for (int it = 0; it < 4; ++it) {
    int p = psub * 1024 + it * 256 + t;
    bf16x8 v;
#pragma unroll
    for (int j = 0; j < 8; ++j) v[j] = ch[j * 4 + it][t];
    *(bf16x8*)(GTz + (long)p * 256 + mc * 8) = v;
  }
}

// ---------------------------------------------------------------------------
// Fl/Fv [b][256][4096] fp32  ->  Xt [img][4096][256] bf16 (img: Fl b0, Fl b1, Fv b0, Fv b1)
__global__ void transpose_cvt(const float* __restrict__ F0, const float* __restrict__ F1,
                              __bf16* __restrict__ Xt) {
  __shared__ float tile[32][33];
  int img = blockIdx.z;
  const float* src = (img < 2 ? F0 : F1) + (long)(img & 1) * (CCH * HWSZ);
  __bf16* dst = Xt + (long)img * (HWSZ * CCH);
  int p0 = blockIdx.x * 32, c0 = blockIdx.y * 32;
  int tx = threadIdx.x, ty = threadIdx.y;
#pragma unroll
  for (int j = 0; j < 32; j += 8)
    tile[ty + j][tx] = src[(long)(c0 + ty + j) * HWSZ + p0 + tx];
  __syncthreads();
#pragma unroll
  for (int j = 0; j < 32; j += 8)
    dst[(long)(p0 + ty + j) * CCH + c0 + tx] = (__bf16)tile[tx][ty + j];
}

// Xt [img][4096][256] -> im2col Cc [img][4096][2304], k = t*256+ci, zero-padded borders
__global__ void im2col_k(const __bf16* __restrict__ Xt, __bf16* __restrict__ Cc) {
  int img = blockIdx.y;
  int e = blockIdx.x * 256 + threadIdx.x;          // < 4096*288
  int p = e / 288;
  int c8 = e - p * 288;
  int t = c8 >> 5;                                 // 0..8
  int ci0 = (c8 & 31) * 8;
  int dy = t / 3 - 1, dx = t - (t / 3) * 3 - 1;
  int y = p >> 6, x = p & 63;
  int yy = y + dy, xx = x + dx;
  const __bf16* src = Xt + (long)img * (HWSZ * CCH);
  __bf16* dst = Cc + (long)img * 9437184 + (long)p * 2304 + t * 256 + ci0;
  uint4 v = make_uint4(0u, 0u, 0u, 0u);
  if ((unsigned)yy < 64u && (unsigned)xx < 64u)
    v = *(const uint4*)(src + (long)(yy * 64 + xx) * CCH + ci0);
  *(uint4*)dst = v;
}

// W[co][ci][3][3] fp32 -> A[co][t*256+ci] bf16, stacked: AL rows (Wqs,Wks,Wvs,Wqc), AV (Wkc,Wvc)
struct W6 { const float* w[6]; };
__global__ void repack_w3(W6 wp, __bf16* __restrict__ AL, __bf16* __restrict__ AV) {
  int zi = blockIdx.y;
  int e = blockIdx.x * 256 + threadIdx.x;          // < 256*2304
  int co = e / 2304;
  int rem = e - co * 2304;
  int t = rem >> 8, ci = rem & 255;
  float v = wp.w[zi][(long)co * 2304 + ci * 9 + t];
  __bf16* dst = (zi < 4) ? (AL + (long)zi * 256 * 2304) : (AV + (long)(zi - 4) * 256 * 2304);
  dst[(long)co * 2304 + rem] = (__bf16)v;
}

__global__ void cvt_bf(const float* __restrict__ s, __bf16* __restrict__ d, int n) {
  int i = blockIdx.x * 256 + threadIdx.x;
  if (i < n) d[i] = (__bf16)s[i];
}

// combine 32 row-chunk partial stats -> column max + 1/sumexp (per z)
__global__ void stats_combine(const float* __restrict__ pm, const float* __restrict__ pl,
                              float* __restrict__ mst, float* __restrict__ lst) {
  int q = blockIdx.x * 256 + threadIdx.x;
  int z = blockIdx.y;
  const float* pmz = pm + (long)z * 32 * 4096;
  const float* plz = pl + (long)z * 32 * 4096;
  float m = -3.0e38f;
#pragma unroll
  for (int rc = 0; rc < 32; ++rc) m = fmaxf(m, pmz[(long)rc * 4096 + q]);
  float l = 0.f;
#pragma unroll
  for (int rc = 0; rc < 32; ++rc)
    l += plz[(long)rc * 4096 + q] * exp2_fast((pmz[(long)rc * 4096 + q] - m) * LOG2E);
  mst[(long)z * 4096 + q] = m;
  lst[(long)z * 4096 + q] = 1.0f / l;
}

// ---------------------------------------------------------------------------
extern "C" void kernel_launch(void* const* d_in, const int* in_sizes, int n_in,
                              void* d_out, int out_size, void* d_ws, size_t ws_size,
                              hipStream_t stream) {
  const float* Fl  = (const float*)d_in[0];
  const float* Fv  = (const float*)d_in[1];
  const float* Wqs = (const float*)d_in[2];  const float* bqs = (const float*)d_in[3];
  const float* Wks = (const float*)d_in[4];  const float* bks = (const float*)d_in[5];
  const float* Wvs = (const float*)d_in[6];  const float* bvs = (const float*)d_in[7];
  const float* Wqc = (const float*)d_in[8];  const float* bqc = (const float*)d_in[9];
  const float* Wkc = (const float*)d_in[10]; const float* bkc = (const float*)d_in[11];
  const float* Wvc = (const float*)d_in[12]; const float* bvc = (const float*)d_in[13];
  const float* Wgs = (const float*)d_in[14]; const float* bgs = (const float*)d_in[15];
  const float* Wfu = (const float*)d_in[16]; const float* bfu = (const float*)d_in[17];

  char* ws = (char*)d_ws;
  size_t off = 0;
  auto take = [&](size_t bytes) -> void* {
    void* p = ws + off; off = (off + bytes + 255) & ~(size_t)255; return p;
  };
  __bf16* QST  = (__bf16*)take(4194304);   // Qs^T  [b][4096][256]
  __bf16* KST  = (__bf16*)take(4194304);
  __bf16* QCT  = (__bf16*)take(4194304);
  __bf16* KCT  = (__bf16*)take(4194304);
  __bf16* VS   = (__bf16*)take(4194304);   // Vs    [b][256][4096]
  __bf16* VC   = (__bf16*)take(4194304);
  __bf16* GT   = (__bf16*)take(4194304);   // reshape-transposed G [b][4096][256]
  __bf16* ZZ   = (__bf16*)take(8388608);   // concat [b][4096][512]
  __bf16* AL   = (__bf16*)take(4718592);   // stacked conv weights [1024][2304]
  __bf16* AV   = (__bf16*)take(2359296);   // [512][2304]
  __bf16* WGSb = (__bf16*)take(131072);
  __bf16* WFSb = (__bf16*)take(262144);
  float*  MST  = (float*)take(32768);      // [2][4096]
  float*  LST  = (float*)take(32768);
  float*  PM   = (float*)take(1048576);    // [2][32][4096]
  float*  PL   = (float*)take(1048576);
  size_t ovl = off;                         // overlay region
  __bf16* Xt = (__bf16*)take(8388608);      // conv phase only
  __bf16* Cc = (__bf16*)take(75497472);     // conv phase only
  size_t needConv = off;
  __bf16* Pb = (__bf16*)(ws + ovl);                  // [2 z][4096][4096] bf16 = 64 MB
  float*  Gp = (float*)(ws + ovl + 67108864);        // [2 z][8 slots][4096*256] fp32 = 64 MB
  size_t needAttn = ovl + 134217728;
  size_t need = needConv > needAttn ? needConv : needAttn;
  if (ws_size < need) return;               // fail cleanly instead of faulting

  const long Z1 = 1048576;                  // per-batch stride (elements) for 256x4096 mats

  transpose_cvt<<<dim3(128, 8, 4), dim3(32, 8), 0, stream>>>(Fl, Fv, Xt);
  im2col_k<<<dim3(4608, 4), 256, 0, stream>>>(Xt, Cc);
  W6 wp; wp.w[0]=Wqs; wp.w[1]=Wks; wp.w[2]=Wvs; wp.w[3]=Wqc; wp.w[4]=Wkc; wp.w[5]=Wvc;
  repack_w3<<<dim3(2304, 6), 256, 0, stream>>>(wp, AL, AV);
  cvt_bf<<<256, 256, 0, stream>>>(Wgs, WGSb, 65536);
  cvt_bf<<<512, 256, 0, stream>>>(Wfu, WFSb, 131072);

  // conv3x3 stacked GEMMs: M=1024 (Qs,Ks,Vs,Qc from Fl), M=512 (Kc,Vc from Fv)
  gemm_bt<M_CONVL><<<dim3(32, 8, 2), 256, 0, stream>>>(
      AL, 0, Cc, 9437184, 4096, 2304,
      QST, KST, VS, QCT, Z1,
      nullptr, 0,
      bqs, bks, bvs, bqc,
      nullptr, 0, nullptr, nullptr, 0, nullptr, nullptr);
  gemm_bt<M_CONVV><<<dim3(32, 4, 2), 256, 0, stream>>>(
      AV, 0, Cc + (long)2 * 9437184, 9437184, 4096, 2304,
      KCT, VC, nullptr, nullptr, Z1,
      nullptr, 0,
      bkc, bvc, nullptr, nullptr,
      nullptr, 0, nullptr, nullptr, 0, nullptr, nullptr);

  for (int br = 0; br < 2; ++br) {
    const __bf16* Qt = br ? QCT : QST;
    const __bf16* Kt = br ? KCT : KST;
    const __bf16* Vv = br ? VC  : VS;
    const float*  rs = br ? Fv  : Fl;
    // Pb = exp(S - m_blk) bf16 + per-(rowblock,column) stats, z-batched
    gemm_bt<M_SSTAT><<<dim3(32, 32, 2), 256, 0, stream>>>(
        Qt, Z1, Kt, Z1, 4096, 256,
        Pb, nullptr, nullptr, nullptr, (long)16777216,
        nullptr, 0,
        nullptr, nullptr, nullptr, nullptr,
        nullptr, 0, nullptr, nullptr, 0, PM, PL);
    stats_combine<<<dim3(16, 2), 256, 0, stream>>>(PM, PL, MST, LST);
    // split-K PV from Pb: G_partial[slot] = (Pb*f)[:, ks] * V^T chunk
    gemm_bt<M_PVK><<<dim3(2, 32, 16), 256, 0, stream>>>(
        Pb, (long)16777216, Vv, Z1, 256, 4096,
        nullptr, nullptr, nullptr, nullptr, 0,
        Gp, 0,
        nullptr, nullptr, nullptr, nullptr,
        nullptr, 0, MST, LST, 0, PM, nullptr);
    reduce_pv<<<dim3(4, 32, 2), 256, 0, stream>>>(Gp, GT);
    // 1x1 conv + bias + residual -> ZZ[:, br*256 .. br*256+255]
    gemm_bt<M_G1><<<dim3(32, 2, 2), 256, 0, stream>>>(
        WGSb, 0, GT, Z1, 4096, 256,
        ZZ, nullptr, nullptr, nullptr, (long)2097152,
        nullptr, 0,
        bgs, nullptr, nullptr, nullptr,
        rs, Z1, nullptr, nullptr, br * 256, nullptr, nullptr);
  }
  // fuse conv 1x1 over 512 channels -> fp32 out
  gemm_bt<M_FUSE><<<dim3(32, 2, 2), 256, 0, stream>>>(
      WFSb, 0, ZZ, (long)2097152, 4096, 512,
      nullptr, nullptr, nullptr, nullptr, 0,
      (float*)d_out, Z1,
      bfu, nullptr, nullptr, nullptr,
      nullptr, 0, nullptr, nullptr, 0, nullptr, nullptr);
}